// Round 7
// baseline (351.475 us; speedup 1.0000x reference)
//
#include <hip/hip_runtime.h>
#include <math.h>

#define T_TOK   500000
#define NF4     8000000      // float4 count of token_embs
#define NTILES  7813         // ceil(500000/64)
#define GRID_F  2048         // 8 1-wave blocks per CU (LDS 16384 B, VGPR<=256)
#define PROW    520          // per-stream partial row: 512 sums + 8 masses

typedef __attribute__((ext_vector_type(8))) short bf16x8;
typedef __attribute__((ext_vector_type(4))) float f32x4;

union FB { bf16x8 v; unsigned u[4]; };

// ws layout (bytes)
#define OFF_PARTA 0u                  // double[GRID_F][128]  (2 MB)
#define OFF_COLF  (2u<<20)            // double[128]
#define OFF_CNT   ((2u<<20) + 4096u)  // int
#define OFF_P7    (4u<<20)            // float[7][GRID_F][PROW] (~29.8 MB)
#define OFF_P2    (36u<<20)           // float[256][PROW]

__device__ __forceinline__ unsigned cvt_pk_bf16(float lo, float hi) {
  unsigned r;
  asm("v_cvt_pk_bf16_f32 %0, %1, %2" : "=v"(r) : "v"(lo), "v"(hi));
  return r;
}

// ---------------- fused-kernel helpers ----------------
__device__ __forceinline__ void issue_q(const float4* __restrict__ x4, int t0m,
                                        int li, int lg,
                                        float4& r0, float4& r1, float4& r2, float4& r3) {
  const int tok = t0m + li;
  if (tok < T_TOK) {
    const float4* p = x4 + (size_t)tok * 16 + lg * 2;
    r0 = p[0]; r1 = p[1]; r2 = p[8]; r3 = p[9];
  } else {
    r0 = r1 = r2 = r3 = make_float4(0.f, 0.f, 0.f, 0.f);
  }
}

__device__ __forceinline__ void issue_g(const float* __restrict__ gum, int tb,
                                        int lane, float (&g)[4]) {
  const int lg = lane >> 4;
  #pragma unroll
  for (int r = 0; r < 4; r++) {
    int T  = tb + lg * 4 + r;
    int Tc = (T < T_TOK) ? T : (T_TOK - 1);
    g[r] = gum[(size_t)Tc * 8 + (lane & 7)];
  }
}

// One 16-token quarter: colstats + bf16 pack + XbfT scatter + dots MFMA +
// 8-cluster softmax (shared max) + 7-variant assign -> Abf pairs.
template<int MM>
__device__ __forceinline__ void process_q(
    const float4& r0, const float4& r1, const float4& r2, const float4& r3,
    const float (&g)[4], int li, int lg, int t0, float c2s,
    const FB* cb, unsigned short* XbfT, unsigned short* Abf,
    float (&msr)[7], float (&s16)[16], float (&q16)[16]) {
  // ---- column stats (f32 lane partials; dims lg*8+j and 32+lg*8+j) ----
  const float xv[16] = {r0.x,r0.y,r0.z,r0.w, r1.x,r1.y,r1.z,r1.w,
                        r2.x,r2.y,r2.z,r2.w, r3.x,r3.y,r3.z,r3.w};
  #pragma unroll
  for (int j = 0; j < 16; j++) { s16[j] += xv[j]; q16[j] += xv[j] * xv[j]; }

  FB xa0, xa1;
  xa0.u[0] = cvt_pk_bf16(r0.x, r0.y); xa0.u[1] = cvt_pk_bf16(r0.z, r0.w);
  xa0.u[2] = cvt_pk_bf16(r1.x, r1.y); xa0.u[3] = cvt_pk_bf16(r1.z, r1.w);
  xa1.u[0] = cvt_pk_bf16(r2.x, r2.y); xa1.u[1] = cvt_pk_bf16(r2.z, r2.w);
  xa1.u[2] = cvt_pk_bf16(r3.x, r3.y); xa1.u[3] = cvt_pk_bf16(r3.z, r3.w);
  // scatter to XbfT: token t = MM*16+li, dims d = lg*8+j (h0), 32+lg*8+j (h1)
  const int tlow  = li & 7;
  const int thigh = MM * 2 + (li >> 3);
  #pragma unroll
  for (int j = 0; j < 8; j++) {
    unsigned w0 = xa0.u[j >> 1], w1 = xa1.u[j >> 1];
    unsigned short h0 = (unsigned short)((j & 1) ? (w0 >> 16) : (w0 & 0xffffu));
    unsigned short h1 = (unsigned short)((j & 1) ? (w1 >> 16) : (w1 & 0xffffu));
    int a0 = (lg * 8 + j) * 64      + (((thigh + j + lg) & 7) << 3)     + tlow;
    int a1 = (32 + lg * 8 + j) * 64 + (((thigh + j + 4 + lg) & 7) << 3) + tlow;
    XbfT[a0] = h0;
    XbfT[a1] = h1;
  }
  // dots: C row = token (lg*4+r), col = cluster li
  f32x4 dC = {0, 0, 0, 0};
  dC = __builtin_amdgcn_mfma_f32_16x16x32_bf16(xa0.v, cb[0].v, dC, 0, 0, 0);
  dC = __builtin_amdgcn_mfma_f32_16x16x32_bf16(xa1.v, cb[1].v, dC, 0, 0, 0);

  // ---- softmax pieces, no cnt mask (shared max over 8 clusters) ----
  float e4[4], pr4[4], rinv4[4];
  bool okr[4];
  #pragma unroll
  for (int r = 0; r < 4; r++) {
    int T = t0 + MM * 16 + lg * 4 + r;
    okr[r] = (T < T_TOK);
    float nz = -__logf(-__logf(g[r]));
    e4[r] = 2.f * dC[r] - c2s + nz;   // logit for (token r, cluster li); x^2 cancels
  }
  float mx[4] = {e4[0], e4[1], e4[2], e4[3]};
  #pragma unroll
  for (int s = 1; s <= 4; s <<= 1) {
    #pragma unroll
    for (int r = 0; r < 4; r++) mx[r] = fmaxf(mx[r], __shfl_xor(mx[r], s));
  }
  #pragma unroll
  for (int r = 0; r < 4; r++) e4[r] = okr[r] ? __expf(e4[r] - mx[r]) : 0.f;
  // inclusive prefix over the 8-lane cluster segment: lane j -> S_{j+1}
  #pragma unroll
  for (int r = 0; r < 4; r++) {
    float p = e4[r];
    float t1 = __shfl_up(p, 1, 8); if ((li & 7) >= 1) p += t1;
    float t2 = __shfl_up(p, 2, 8); if ((li & 7) >= 2) p += t2;
    float t4 = __shfl_up(p, 4, 8); if ((li & 7) >= 4) p += t4;
    pr4[r] = p;
    asm("v_rcp_f32 %0, %1" : "=v"(rinv4[r]) : "v"(p));
  }
  // ---- 7 variants packed pairwise into Abf[p] rows {li, li+8} ----
  #pragma unroll
  for (int p = 0; p < 4; p++) {
    const int vlo = 2 + 2 * p;
    float alo[4];
    #pragma unroll
    for (int r = 0; r < 4; r++) {
      float rl = __shfl(rinv4[r], vlo - 1, 8);
      alo[r] = (li < vlo && okr[r]) ? e4[r] * rl : 0.f;
      msr[2 * p] += alo[r];
    }
    if (li < 8) {
      unsigned p0 = cvt_pk_bf16(alo[0], alo[1]), p1 = cvt_pk_bf16(alo[2], alo[3]);
      int aa = li * 64 + (((MM * 2 + (lg >> 1) + li) & 7) << 3) + ((lg & 1) << 2);
      *(uint2*)&Abf[p * 1024 + aa] = make_uint2(p0, p1);
    }
    if (p < 3) {
      const int vhi = 3 + 2 * p;
      float ahi[4];
      #pragma unroll
      for (int r = 0; r < 4; r++) {
        float rh = __shfl(rinv4[r], vhi - 1, 8);
        ahi[r] = (li < vhi && okr[r]) ? e4[r] * rh : 0.f;
        msr[2 * p + 1] += ahi[r];
      }
      if (li < 8) {
        unsigned p0 = cvt_pk_bf16(ahi[0], ahi[1]), p1 = cvt_pk_bf16(ahi[2], ahi[3]);
        // row = li+8: (ROW&7)=li, (ROW>>3)=1
        int aa = (li + 8) * 64 + (((MM * 2 + (lg >> 1) + li + 1) & 7) << 3) + ((lg & 1) << 2);
        *(uint2*)&Abf[p * 1024 + aa] = make_uint2(p0, p1);
      }
    }
  }
}

// ---------------- fused single-pass kernel ----------------
__global__ __launch_bounds__(64, 2) void k_fused(const float4* __restrict__ x4,
                                                 const float* __restrict__ gum,
                                                 const float* __restrict__ cm,
                                                 double* __restrict__ parta,
                                                 float* __restrict__ P7) {
  const int lane = threadIdx.x & 63;
  const int li = lane & 15, lg = lane >> 4;
  __shared__ unsigned short LDSH[8192];  // XbfT[4096] ; Abf[4][1024] -> 16384 B
  unsigned short* XbfT = LDSH;
  unsigned short* Abf  = LDSH + 4096;

  // centers B-frag + ||c||^2 computed locally from f32 centers
  FB cb[2];
  float c2s;
  {
    float ssq = 0.f;
    #pragma unroll
    for (int h = 0; h < 2; h++) {
      float4 u0 = make_float4(0.f, 0.f, 0.f, 0.f), u1 = u0;
      if (li < 8) {
        const float4* cp = (const float4*)(cm + li * 64 + h * 32 + lg * 8);
        u0 = cp[0]; u1 = cp[1];
      }
      cb[h].u[0] = cvt_pk_bf16(u0.x, u0.y); cb[h].u[1] = cvt_pk_bf16(u0.z, u0.w);
      cb[h].u[2] = cvt_pk_bf16(u1.x, u1.y); cb[h].u[3] = cvt_pk_bf16(u1.z, u1.w);
      ssq += u0.x*u0.x + u0.y*u0.y + u0.z*u0.z + u0.w*u0.w
           + u1.x*u1.x + u1.y*u1.y + u1.z*u1.z + u1.w*u1.w;
    }
    ssq += __shfl_xor(ssq, 16);
    ssq += __shfl_xor(ssq, 32);
    c2s = ssq;
  }

  f32x4 acc[4][4];  // [pair][n]
  #pragma unroll
  for (int p = 0; p < 4; p++)
    #pragma unroll
    for (int n = 0; n < 4; n++) acc[p][n] = (f32x4){0, 0, 0, 0};
  float msr[7] = {0, 0, 0, 0, 0, 0, 0};
  float s16[16], q16[16];
  #pragma unroll
  for (int j = 0; j < 16; j++) { s16[j] = 0.f; q16[j] = 0.f; }

  float4 a0, a1, a2, a3, b0, b1, b2, b3;
  float ga[4], gb[4];
  int tile = blockIdx.x;
  if (tile < NTILES) {
    issue_q(x4, tile * 64, li, lg, a0, a1, a2, a3);
    issue_g(gum, tile * 64, lane, ga);
  }

  for (; tile < NTILES; tile += GRID_F) {
    const int t0 = tile * 64;
    issue_q(x4, t0 + 16, li, lg, b0, b1, b2, b3);
    issue_g(gum, t0 + 16, lane, gb);
    process_q<0>(a0, a1, a2, a3, ga, li, lg, t0, c2s, cb, XbfT, Abf, msr, s16, q16);
    issue_q(x4, t0 + 32, li, lg, a0, a1, a2, a3);
    issue_g(gum, t0 + 32, lane, ga);
    process_q<1>(b0, b1, b2, b3, gb, li, lg, t0, c2s, cb, XbfT, Abf, msr, s16, q16);
    issue_q(x4, t0 + 48, li, lg, b0, b1, b2, b3);
    issue_g(gum, t0 + 48, lane, gb);
    process_q<2>(a0, a1, a2, a3, ga, li, lg, t0, c2s, cb, XbfT, Abf, msr, s16, q16);
    if (tile + GRID_F < NTILES) {
      issue_q(x4, (tile + GRID_F) * 64, li, lg, a0, a1, a2, a3);
      issue_g(gum, (tile + GRID_F) * 64, lane, ga);
    }
    process_q<3>(b0, b1, b2, b3, gb, li, lg, t0, c2s, cb, XbfT, Abf, msr, s16, q16);

    // wave-local LDS fence (1-wave block): scatter/Abf writes -> reads
    asm volatile("s_waitcnt lgkmcnt(0)" ::: "memory");

    // accumulation: per pair, cluster_sums += assign_pair^T * X
    FB af[4][2];
    const int abase = li * 64;
    const int asw   = (li & 7) + (li >> 3);
    #pragma unroll
    for (int p = 0; p < 4; p++) {
      af[p][0].v = *(bf16x8*)&Abf[p * 1024 + abase + (((lg + asw) & 7) << 3)];
      af[p][1].v = *(bf16x8*)&Abf[p * 1024 + abase + (((4 + lg + asw) & 7) << 3)];
    }
    #pragma unroll
    for (int n = 0; n < 4; n++) {
      const int d  = n * 16 + li;
      const int dl = (li & 7) + 2 * n + (li >> 3);
      bf16x8 xb0 = *(bf16x8*)&XbfT[d * 64 + (((lg + dl) & 7) << 3)];
      #pragma unroll
      for (int p = 0; p < 4; p++)
        acc[p][n] = __builtin_amdgcn_mfma_f32_16x16x32_bf16(af[p][0].v, xb0, acc[p][n], 0, 0, 0);
      bf16x8 xb1 = *(bf16x8*)&XbfT[d * 64 + (((4 + lg + dl) & 7) << 3)];
      #pragma unroll
      for (int p = 0; p < 4; p++)
        acc[p][n] = __builtin_amdgcn_mfma_f32_16x16x32_bf16(af[p][1].v, xb1, acc[p][n], 0, 0, 0);
    }
    asm volatile("s_waitcnt lgkmcnt(0)" ::: "memory");
  }

  // ---- colstats block reduce (over li) -> f64 partials ----
  #pragma unroll
  for (int off = 1; off <= 8; off <<= 1) {
    #pragma unroll
    for (int j = 0; j < 16; j++) {
      s16[j] += __shfl_xor(s16[j], off);
      q16[j] += __shfl_xor(q16[j], off);
    }
  }
  if (li == 0) {
    #pragma unroll
    for (int j = 0; j < 8; j++) {
      parta[(size_t)blockIdx.x * 128 + lg * 8 + j]            = (double)s16[j];
      parta[(size_t)blockIdx.x * 128 + 32 + lg * 8 + j]       = (double)s16[8 + j];
      parta[(size_t)blockIdx.x * 128 + 64 + lg * 8 + j]       = (double)q16[j];
      parta[(size_t)blockIdx.x * 128 + 64 + 32 + lg * 8 + j]  = (double)q16[8 + j];
    }
  }

  // ---- write 7 variant partial rows ----
  // pair p: rows 0..7 = variant 2+2p, rows 8..15 = variant 3+2p (p<3)
  #pragma unroll
  for (int p = 0; p < 4; p++) {
    const int vlo = 2 + 2 * p;
    #pragma unroll
    for (int n = 0; n < 4; n++) {
      #pragma unroll
      for (int r = 0; r < 4; r++) {
        int row = lg * 4 + r;
        if (row < 8)
          P7[((size_t)(vlo - 2) * GRID_F + blockIdx.x) * PROW + row * 64 + n * 16 + li] = acc[p][n][r];
        else if (p < 3)
          P7[((size_t)(vlo - 1) * GRID_F + blockIdx.x) * PROW + (row - 8) * 64 + n * 16 + li] = acc[p][n][r];
      }
    }
  }
  #pragma unroll
  for (int v = 0; v < 7; v++) {
    float m = msr[v];
    m += __shfl_xor(m, 16);
    m += __shfl_xor(m, 32);
    if (lane < 8)
      P7[((size_t)v * GRID_F + blockIdx.x) * PROW + 512 + lane] = m;
  }
}

// ---------------- column reduce (2048 partials) ----------------
__global__ __launch_bounds__(256) void k_colreduce(const double* __restrict__ parta,
                                                   double* __restrict__ colf) {
  const int c = blockIdx.x;  // 0..127
  double t = 0;
  for (int b = threadIdx.x; b < GRID_F; b += 256) t += parta[(size_t)b * 128 + c];
  __shared__ double r[256];
  r[threadIdx.x] = t;
  __syncthreads();
  for (int s = 128; s > 0; s >>= 1) {
    if (threadIdx.x < s) r[threadIdx.x] += r[threadIdx.x + s];
    __syncthreads();
  }
  if (threadIdx.x == 0) colf[c] = r[0];
}

// ---------------- variance -> cluster_count ----------------
__global__ __launch_bounds__(64) void k_cnt(const double* __restrict__ colf,
                                            int* __restrict__ cnt) {
  const int c = threadIdx.x;  // 0..63
  double sum = colf[c], sq = colf[64 + c];
  double var = (sq - sum * sum / (double)T_TOK) / (double)(T_TOK - 1);
  for (int off = 32; off; off >>= 1) var += __shfl_xor(var, off);
  if (c == 0) {
    double vm = var / 64.0;
    int kk = (int)floor(vm * 5.0 + 2.0);
    if (kk < 2) kk = 2;
    if (kk > 8) kk = 8;
    *cnt = kk;
  }
}

// ---------------- select winning variant, coalesced reduce 2048 -> 256 ----------------
__global__ __launch_bounds__(64) void k_redsel1(const float* __restrict__ P7,
                                                const int* __restrict__ cntp,
                                                float* __restrict__ P2) {
  const int v = *cntp - 2;
  const float* S = P7 + (size_t)v * GRID_F * PROW;
  const int b = blockIdx.x;  // 0..255, rows b*8 .. b*8+7
  for (int c = threadIdx.x; c < PROW; c += 64) {
    float s = 0.f;
    #pragma unroll
    for (int i = 0; i < 8; i++) s += S[(size_t)(b * 8 + i) * PROW + c];
    P2[(size_t)b * PROW + c] = s;
  }
}

// ---------------- final reduce + normalize ----------------
__global__ __launch_bounds__(64) void k_red2(const float* __restrict__ P2,
                                             const int* __restrict__ cntp,
                                             float* __restrict__ out) {
  const int kd = blockIdx.x;  // 0..511
  const int k = kd >> 6;
  const int t = threadIdx.x;
  float s = 0.f, m = 0.f;
  #pragma unroll
  for (int i = 0; i < 4; i++) {
    int r = t + i * 64;
    s += P2[(size_t)r * PROW + kd];
    m += P2[(size_t)r * PROW + 512 + k];
  }
  for (int off = 1; off <= 32; off <<= 1) {
    s += __shfl_xor(s, off);
    m += __shfl_xor(m, off);
  }
  if (t == 0) {
    int cnt = *cntp;
    out[kd] = (k < cnt) ? s / (m + 1e-8f) : 0.f;
  }
}

extern "C" void kernel_launch(void* const* d_in, const int* in_sizes, int n_in,
                              void* d_out, int out_size, void* d_ws, size_t ws_size,
                              hipStream_t stream) {
  const float* embs = (const float*)d_in[0];
  const float* gum  = (const float*)d_in[1];
  const float* cent = (const float*)d_in[2];
  char* ws = (char*)d_ws;
  double* parta = (double*)(ws + OFF_PARTA);
  double* colf  = (double*)(ws + OFF_COLF);
  int*    cnt   = (int*)   (ws + OFF_CNT);
  float*  P7    = (float*) (ws + OFF_P7);
  float*  P2    = (float*) (ws + OFF_P2);

  k_fused<<<GRID_F, 64, 0, stream>>>((const float4*)embs, gum, cent, parta, P7);
  k_colreduce<<<128, 256, 0, stream>>>(parta, colf);
  k_cnt<<<1, 64, 0, stream>>>(colf, cnt);
  k_redsel1<<<256, 64, 0, stream>>>(P7, cnt, P2);
  k_red2<<<512, 64, 0, stream>>>(P2, cnt, (float*)d_out);
}

// Round 8
// 252.110 us; speedup vs baseline: 1.3941x; 1.3941x over previous
//
#include <hip/hip_runtime.h>
#include <math.h>

#define T_TOK   500000
#define NF4     8000000      // float4 count of token_embs
#define NTILES  7813         // ceil(500000/64)
#define GRID_F  1954         // fused: every stream does exactly 4 tiles (last 3 do 3)
#define GRID_FB 2048         // fallback grid
#define PROW    520          // partial row: 512 sums + 8 masses

typedef __attribute__((ext_vector_type(8))) short bf16x8;
typedef __attribute__((ext_vector_type(4))) float f32x4;

union FB { bf16x8 v; unsigned u[4]; };

// ws layout (bytes)
#define OFF_PARTA 0u                  // double[GRID_F][128]  (~2 MB)
#define OFF_COLF  (2u<<20)            // double[128]
#define OFF_CNT   ((2u<<20) + 1024u)  // int
#define OFF_P4    (4u<<20)            // float[4][GRID_F][PROW] (~16.3 MB)
#define OFF_PF    (22u<<20)           // float[GRID_FB][PROW]   (~4.3 MB)
#define OFF_P2    (28u<<20)           // float[256][PROW]

__device__ __forceinline__ unsigned cvt_pk_bf16(float lo, float hi) {
  unsigned r;
  asm("v_cvt_pk_bf16_f32 %0, %1, %2" : "=v"(r) : "v"(lo), "v"(hi));
  return r;
}

// ---------------- shared helpers ----------------
__device__ __forceinline__ void issue_q(const float4* __restrict__ x4, int t0m,
                                        int li, int lg,
                                        float4& r0, float4& r1, float4& r2, float4& r3) {
  const int tok = t0m + li;
  if (tok < T_TOK) {
    const float4* p = x4 + (size_t)tok * 16 + lg * 2;
    r0 = p[0]; r1 = p[1]; r2 = p[8]; r3 = p[9];
  } else {
    r0 = r1 = r2 = r3 = make_float4(0.f, 0.f, 0.f, 0.f);
  }
}

__device__ __forceinline__ void issue_g(const float* __restrict__ gum, int tb,
                                        int lane, float (&g)[4]) {
  const int lg = lane >> 4;
  #pragma unroll
  for (int r = 0; r < 4; r++) {
    int T  = tb + lg * 4 + r;
    int Tc = (T < T_TOK) ? T : (T_TOK - 1);
    g[r] = gum[(size_t)Tc * 8 + (lane & 7)];
  }
}

// load centers fragment + ||c||^2 (lane li<8 gets cluster li)
__device__ __forceinline__ void load_centers(const float* __restrict__ cm,
                                             int li, int lg, FB (&cb)[2], float& c2s) {
  float ssq = 0.f;
  #pragma unroll
  for (int h = 0; h < 2; h++) {
    float4 u0 = make_float4(0.f, 0.f, 0.f, 0.f), u1 = u0;
    if (li < 8) {
      const float4* cp = (const float4*)(cm + li * 64 + h * 32 + lg * 8);
      u0 = cp[0]; u1 = cp[1];
    }
    cb[h].u[0] = cvt_pk_bf16(u0.x, u0.y); cb[h].u[1] = cvt_pk_bf16(u0.z, u0.w);
    cb[h].u[2] = cvt_pk_bf16(u1.x, u1.y); cb[h].u[3] = cvt_pk_bf16(u1.z, u1.w);
    ssq += u0.x*u0.x + u0.y*u0.y + u0.z*u0.z + u0.w*u0.w
         + u1.x*u1.x + u1.y*u1.y + u1.z*u1.z + u1.w*u1.w;
  }
  ssq += __shfl_xor(ssq, 16);
  ssq += __shfl_xor(ssq, 32);
  c2s = ssq;
}

// ---------------- fused process: stats + scatter + dots + spec softmax ----------------
template<int MM>
__device__ __forceinline__ void process_q(
    const float4& r0, const float4& r1, const float4& r2, const float4& r3,
    const float (&g)[4], int li, int lg, int t0, float c2s,
    const FB* cb, unsigned short* XbfT, unsigned short* Abf,
    float (&msr)[4], float (&s16)[16], float (&q16)[16]) {
  // column stats (f32 lane partials; dims lg*8+j and 32+lg*8+j)
  const float xv[16] = {r0.x,r0.y,r0.z,r0.w, r1.x,r1.y,r1.z,r1.w,
                        r2.x,r2.y,r2.z,r2.w, r3.x,r3.y,r3.z,r3.w};
  #pragma unroll
  for (int j = 0; j < 16; j++) { s16[j] += xv[j]; q16[j] += xv[j] * xv[j]; }

  FB xa0, xa1;
  xa0.u[0] = cvt_pk_bf16(r0.x, r0.y); xa0.u[1] = cvt_pk_bf16(r0.z, r0.w);
  xa0.u[2] = cvt_pk_bf16(r1.x, r1.y); xa0.u[3] = cvt_pk_bf16(r1.z, r1.w);
  xa1.u[0] = cvt_pk_bf16(r2.x, r2.y); xa1.u[1] = cvt_pk_bf16(r2.z, r2.w);
  xa1.u[2] = cvt_pk_bf16(r3.x, r3.y); xa1.u[3] = cvt_pk_bf16(r3.z, r3.w);
  const int tlow  = li & 7;
  const int thigh = MM * 2 + (li >> 3);
  #pragma unroll
  for (int j = 0; j < 8; j++) {
    unsigned w0 = xa0.u[j >> 1], w1 = xa1.u[j >> 1];
    unsigned short h0 = (unsigned short)((j & 1) ? (w0 >> 16) : (w0 & 0xffffu));
    unsigned short h1 = (unsigned short)((j & 1) ? (w1 >> 16) : (w1 & 0xffffu));
    int a0 = (lg * 8 + j) * 64      + (((thigh + j + lg) & 7) << 3)     + tlow;
    int a1 = (32 + lg * 8 + j) * 64 + (((thigh + j + 4 + lg) & 7) << 3) + tlow;
    XbfT[a0] = h0;
    XbfT[a1] = h1;
  }
  f32x4 dC = {0, 0, 0, 0};
  dC = __builtin_amdgcn_mfma_f32_16x16x32_bf16(xa0.v, cb[0].v, dC, 0, 0, 0);
  dC = __builtin_amdgcn_mfma_f32_16x16x32_bf16(xa1.v, cb[1].v, dC, 0, 0, 0);

  // softmax pieces, shared max over all 8 clusters (identical across variants)
  float e4[4], rinv4[4];
  bool okr[4];
  #pragma unroll
  for (int r = 0; r < 4; r++) {
    int T = t0 + MM * 16 + lg * 4 + r;
    okr[r] = (T < T_TOK);
    float nz = -__logf(-__logf(g[r]));
    e4[r] = 2.f * dC[r] - c2s + nz;   // x^2 cancels in softmax
  }
  float mx[4] = {e4[0], e4[1], e4[2], e4[3]};
  #pragma unroll
  for (int s = 1; s <= 4; s <<= 1) {
    #pragma unroll
    for (int r = 0; r < 4; r++) mx[r] = fmaxf(mx[r], __shfl_xor(mx[r], s));
  }
  #pragma unroll
  for (int r = 0; r < 4; r++) e4[r] = okr[r] ? __expf(e4[r] - mx[r]) : 0.f;
  // inclusive prefix over the 8-lane cluster segment: lane j -> 1/S_{j+1}
  #pragma unroll
  for (int r = 0; r < 4; r++) {
    float p = e4[r];
    float t1 = __shfl_up(p, 1, 8); if ((li & 7) >= 1) p += t1;
    float t2 = __shfl_up(p, 2, 8); if ((li & 7) >= 2) p += t2;
    float t4 = __shfl_up(p, 4, 8); if ((li & 7) >= 4) p += t4;
    asm("v_rcp_f32 %0, %1" : "=v"(rinv4[r]) : "v"(p));
  }
  // variants {5,6,7,8} packed pairwise into Abf[p] rows {li, li+8}
  #pragma unroll
  for (int p = 0; p < 2; p++) {
    const int vlo = 5 + 2 * p, vhi = 6 + 2 * p;
    float alo[4], ahi[4];
    #pragma unroll
    for (int r = 0; r < 4; r++) {
      float rl = __shfl(rinv4[r], vlo - 1, 8);
      float rh = __shfl(rinv4[r], vhi - 1, 8);
      alo[r] = (li < vlo && okr[r]) ? e4[r] * rl : 0.f;
      ahi[r] = (li < vhi && okr[r]) ? e4[r] * rh : 0.f;
      msr[2 * p]     += alo[r];
      msr[2 * p + 1] += ahi[r];
    }
    if (li < 8) {
      unsigned p0 = cvt_pk_bf16(alo[0], alo[1]), p1 = cvt_pk_bf16(alo[2], alo[3]);
      int aa = li * 64 + (((MM * 2 + (lg >> 1) + li) & 7) << 3) + ((lg & 1) << 2);
      *(uint2*)&Abf[p * 1024 + aa] = make_uint2(p0, p1);
      unsigned q0 = cvt_pk_bf16(ahi[0], ahi[1]), q1 = cvt_pk_bf16(ahi[2], ahi[3]);
      int ab = (li + 8) * 64 + (((MM * 2 + (lg >> 1) + li + 1) & 7) << 3) + ((lg & 1) << 2);
      *(uint2*)&Abf[p * 1024 + ab] = make_uint2(q0, q1);
    }
  }
}

// ---------------- fused single-pass kernel ----------------
__global__ __launch_bounds__(64, 1) void k_fused(const float4* __restrict__ x4,
                                                 const float* __restrict__ gum,
                                                 const float* __restrict__ cm,
                                                 double* __restrict__ parta,
                                                 float* __restrict__ P4) {
  const int lane = threadIdx.x & 63;
  const int li = lane & 15, lg = lane >> 4;
  __shared__ unsigned short LDSH[6144];  // XbfT[4096] ; Abf[2][1024] -> 12288 B
  unsigned short* XbfT = LDSH;
  unsigned short* Abf  = LDSH + 4096;

  FB cb[2];
  float c2s;
  load_centers(cm, li, lg, cb, c2s);

  f32x4 acc[2][4];
  #pragma unroll
  for (int p = 0; p < 2; p++)
    #pragma unroll
    for (int n = 0; n < 4; n++) acc[p][n] = (f32x4){0, 0, 0, 0};
  float msr[4] = {0, 0, 0, 0};
  float s16[16], q16[16];
  #pragma unroll
  for (int j = 0; j < 16; j++) { s16[j] = 0.f; q16[j] = 0.f; }

  float4 a0, a1, a2, a3, b0, b1, b2, b3;
  float ga[4], gb[4];
  int tile = blockIdx.x;
  if (tile < NTILES) {
    issue_q(x4, tile * 64, li, lg, a0, a1, a2, a3);
    issue_g(gum, tile * 64, lane, ga);
  }

  for (; tile < NTILES; tile += GRID_F) {
    const int t0 = tile * 64;
    issue_q(x4, t0 + 16, li, lg, b0, b1, b2, b3);
    issue_g(gum, t0 + 16, lane, gb);
    process_q<0>(a0, a1, a2, a3, ga, li, lg, t0, c2s, cb, XbfT, Abf, msr, s16, q16);
    issue_q(x4, t0 + 32, li, lg, a0, a1, a2, a3);
    issue_g(gum, t0 + 32, lane, ga);
    process_q<1>(b0, b1, b2, b3, gb, li, lg, t0, c2s, cb, XbfT, Abf, msr, s16, q16);
    issue_q(x4, t0 + 48, li, lg, b0, b1, b2, b3);
    issue_g(gum, t0 + 48, lane, gb);
    process_q<2>(a0, a1, a2, a3, ga, li, lg, t0, c2s, cb, XbfT, Abf, msr, s16, q16);
    if (tile + GRID_F < NTILES) {
      issue_q(x4, (tile + GRID_F) * 64, li, lg, a0, a1, a2, a3);
      issue_g(gum, (tile + GRID_F) * 64, lane, ga);
    }
    process_q<3>(b0, b1, b2, b3, gb, li, lg, t0, c2s, cb, XbfT, Abf, msr, s16, q16);

    // wave-local LDS fence (1-wave block): scatter/Abf writes -> reads
    asm volatile("s_waitcnt lgkmcnt(0)" ::: "memory");

    FB af[2][2];
    const int abase = li * 64;
    const int asw   = (li & 7) + (li >> 3);
    #pragma unroll
    for (int p = 0; p < 2; p++) {
      af[p][0].v = *(bf16x8*)&Abf[p * 1024 + abase + (((lg + asw) & 7) << 3)];
      af[p][1].v = *(bf16x8*)&Abf[p * 1024 + abase + (((4 + lg + asw) & 7) << 3)];
    }
    #pragma unroll
    for (int n = 0; n < 4; n++) {
      const int d  = n * 16 + li;
      const int dl = (li & 7) + 2 * n + (li >> 3);
      bf16x8 xb0 = *(bf16x8*)&XbfT[d * 64 + (((lg + dl) & 7) << 3)];
      #pragma unroll
      for (int p = 0; p < 2; p++)
        acc[p][n] = __builtin_amdgcn_mfma_f32_16x16x32_bf16(af[p][0].v, xb0, acc[p][n], 0, 0, 0);
      bf16x8 xb1 = *(bf16x8*)&XbfT[d * 64 + (((4 + lg + dl) & 7) << 3)];
      #pragma unroll
      for (int p = 0; p < 2; p++)
        acc[p][n] = __builtin_amdgcn_mfma_f32_16x16x32_bf16(af[p][1].v, xb1, acc[p][n], 0, 0, 0);
    }
    asm volatile("s_waitcnt lgkmcnt(0)" ::: "memory");
  }

  // colstats block reduce (over li) -> f64 partials
  #pragma unroll
  for (int off = 1; off <= 8; off <<= 1) {
    #pragma unroll
    for (int j = 0; j < 16; j++) {
      s16[j] += __shfl_xor(s16[j], off);
      q16[j] += __shfl_xor(q16[j], off);
    }
  }
  if (li == 0) {
    #pragma unroll
    for (int j = 0; j < 8; j++) {
      parta[(size_t)blockIdx.x * 128 + lg * 8 + j]           = (double)s16[j];
      parta[(size_t)blockIdx.x * 128 + 32 + lg * 8 + j]      = (double)s16[8 + j];
      parta[(size_t)blockIdx.x * 128 + 64 + lg * 8 + j]      = (double)q16[j];
      parta[(size_t)blockIdx.x * 128 + 64 + 32 + lg * 8 + j] = (double)q16[8 + j];
    }
  }

  // variant partial rows: pair p -> slot 2p (rows 0-7), slot 2p+1 (rows 8-15)
  #pragma unroll
  for (int p = 0; p < 2; p++) {
    #pragma unroll
    for (int n = 0; n < 4; n++) {
      #pragma unroll
      for (int r = 0; r < 4; r++) {
        int row = lg * 4 + r;
        if (row < 8)
          P4[((size_t)(2 * p) * GRID_F + blockIdx.x) * PROW + row * 64 + n * 16 + li] = acc[p][n][r];
        else
          P4[((size_t)(2 * p + 1) * GRID_F + blockIdx.x) * PROW + (row - 8) * 64 + n * 16 + li] = acc[p][n][r];
      }
    }
  }
  #pragma unroll
  for (int v = 0; v < 4; v++) {
    float m = msr[v];
    m += __shfl_xor(m, 16);
    m += __shfl_xor(m, 32);
    if (lane < 8)
      P4[((size_t)v * GRID_F + blockIdx.x) * PROW + 512 + lane] = m;
  }
}

// ---------------- column reduce ----------------
__global__ __launch_bounds__(256) void k_colreduce(const double* __restrict__ parta,
                                                   double* __restrict__ colf) {
  const int c = blockIdx.x;  // 0..127
  double t = 0;
  for (int b = threadIdx.x; b < GRID_F; b += 256) t += parta[(size_t)b * 128 + c];
  __shared__ double r[256];
  r[threadIdx.x] = t;
  __syncthreads();
  for (int s = 128; s > 0; s >>= 1) {
    if (threadIdx.x < s) r[threadIdx.x] += r[threadIdx.x + s];
    __syncthreads();
  }
  if (threadIdx.x == 0) colf[c] = r[0];
}

// ---------------- variance -> cluster_count ----------------
__global__ __launch_bounds__(64) void k_cnt(const double* __restrict__ colf,
                                            int* __restrict__ cnt) {
  const int c = threadIdx.x;  // 0..63
  double sum = colf[c], sq = colf[64 + c];
  double var = (sq - sum * sum / (double)T_TOK) / (double)(T_TOK - 1);
  for (int off = 32; off; off >>= 1) var += __shfl_xor(var, off);
  if (c == 0) {
    double vm = var / 64.0;
    int kk = (int)floor(vm * 5.0 + 2.0);
    if (kk < 2) kk = 2;
    if (kk > 8) kk = 8;
    *cnt = kk;
  }
}

// ---------------- fallback (round-6 verified k_main, runs only if cnt<5) ----------------
template<int MM>
__device__ __forceinline__ void process_fb(
    const float4& r0, const float4& r1, const float4& r2, const float4& r3,
    const float (&gg)[4][4], int li, int lg, int t0, int cnt, float c2s,
    const FB* cb, unsigned short* XbfT, unsigned short* Abf, float& msr) {
  FB xa0, xa1;
  xa0.u[0] = cvt_pk_bf16(r0.x, r0.y); xa0.u[1] = cvt_pk_bf16(r0.z, r0.w);
  xa0.u[2] = cvt_pk_bf16(r1.x, r1.y); xa0.u[3] = cvt_pk_bf16(r1.z, r1.w);
  xa1.u[0] = cvt_pk_bf16(r2.x, r2.y); xa1.u[1] = cvt_pk_bf16(r2.z, r2.w);
  xa1.u[2] = cvt_pk_bf16(r3.x, r3.y); xa1.u[3] = cvt_pk_bf16(r3.z, r3.w);
  const int tlow  = li & 7;
  const int thigh = MM * 2 + (li >> 3);
  #pragma unroll
  for (int j = 0; j < 8; j++) {
    unsigned w0 = xa0.u[j >> 1], w1 = xa1.u[j >> 1];
    unsigned short h0 = (unsigned short)((j & 1) ? (w0 >> 16) : (w0 & 0xffffu));
    unsigned short h1 = (unsigned short)((j & 1) ? (w1 >> 16) : (w1 & 0xffffu));
    int a0 = (lg * 8 + j) * 64      + (((thigh + j + lg) & 7) << 3)     + tlow;
    int a1 = (32 + lg * 8 + j) * 64 + (((thigh + j + 4 + lg) & 7) << 3) + tlow;
    XbfT[a0] = h0;
    XbfT[a1] = h1;
  }
  f32x4 dC = {0, 0, 0, 0};
  dC = __builtin_amdgcn_mfma_f32_16x16x32_bf16(xa0.v, cb[0].v, dC, 0, 0, 0);
  dC = __builtin_amdgcn_mfma_f32_16x16x32_bf16(xa1.v, cb[1].v, dC, 0, 0, 0);
  float lgt[4], a4[4];
  bool okr[4];
  #pragma unroll
  for (int r = 0; r < 4; r++) {
    int T = t0 + MM * 16 + lg * 4 + r;
    float nz = -__logf(-__logf(gg[MM][r]));
    bool ok = (li < cnt) && (T < T_TOK);
    okr[r] = ok;
    lgt[r] = ok ? (2.f * dC[r] - c2s + nz) : -1e30f;
  }
  float mx[4] = {lgt[0], lgt[1], lgt[2], lgt[3]};
  #pragma unroll
  for (int s = 1; s <= 4; s <<= 1) {
    #pragma unroll
    for (int r = 0; r < 4; r++) mx[r] = fmaxf(mx[r], __shfl_xor(mx[r], s));
  }
  float e[4], sm[4];
  #pragma unroll
  for (int r = 0; r < 4; r++) { e[r] = __expf(lgt[r] - mx[r]); sm[r] = e[r]; }
  #pragma unroll
  for (int s = 1; s <= 4; s <<= 1) {
    #pragma unroll
    for (int r = 0; r < 4; r++) sm[r] += __shfl_xor(sm[r], s);
  }
  #pragma unroll
  for (int r = 0; r < 4; r++) {
    float inv;
    asm("v_rcp_f32 %0, %1" : "=v"(inv) : "v"(sm[r]));
    a4[r] = okr[r] ? e[r] * inv : 0.f;
    msr += a4[r];
  }
  unsigned p0 = cvt_pk_bf16(a4[0], a4[1]), p1 = cvt_pk_bf16(a4[2], a4[3]);
  int aa = li * 64 + (((MM * 2 + (lg >> 1) + (li & 7) + (li >> 3)) & 7) << 3) + ((lg & 1) << 2);
  *(uint2*)&Abf[aa] = make_uint2(p0, p1);
}

__global__ __launch_bounds__(64) void k_fallback(const float4* __restrict__ x4,
                                                 const float* __restrict__ gum,
                                                 const float* __restrict__ cm,
                                                 const int* __restrict__ cntp,
                                                 float* __restrict__ Pf) {
  const int cnt = *cntp;
  if (cnt >= 5) return;  // speculative path covers {5..8}
  const int lane = threadIdx.x & 63;
  const int li = lane & 15, lg = lane >> 4;
  __shared__ unsigned short LDSH[5120];
  unsigned short* XbfT = LDSH;
  unsigned short* Abf  = LDSH + 4096;

  FB cb[2];
  float c2s;
  load_centers(cm, li, lg, cb, c2s);

  f32x4 acc[4] = {{0,0,0,0},{0,0,0,0},{0,0,0,0},{0,0,0,0}};
  float msr = 0.f;

  float4 a0, a1, a2, a3, b0, b1, b2, b3;
  int tile = blockIdx.x;
  if (tile < NTILES) issue_q(x4, tile * 64, li, lg, a0, a1, a2, a3);

  for (; tile < NTILES; tile += GRID_FB) {
    const int t0 = tile * 64;
    float gg[4][4];
    #pragma unroll
    for (int m = 0; m < 4; m++) {
      #pragma unroll
      for (int r = 0; r < 4; r++) {
        int T = t0 + m * 16 + lg * 4 + r;
        int Tc = (T < T_TOK) ? T : (T_TOK - 1);
        gg[m][r] = gum[(size_t)Tc * 8 + (li & 7)];
      }
    }
    issue_q(x4, t0 + 16, li, lg, b0, b1, b2, b3);
    process_fb<0>(a0, a1, a2, a3, gg, li, lg, t0, cnt, c2s, cb, XbfT, Abf, msr);
    issue_q(x4, t0 + 32, li, lg, a0, a1, a2, a3);
    process_fb<1>(b0, b1, b2, b3, gg, li, lg, t0, cnt, c2s, cb, XbfT, Abf, msr);
    issue_q(x4, t0 + 48, li, lg, b0, b1, b2, b3);
    process_fb<2>(a0, a1, a2, a3, gg, li, lg, t0, cnt, c2s, cb, XbfT, Abf, msr);
    if (tile + GRID_FB < NTILES)
      issue_q(x4, (tile + GRID_FB) * 64, li, lg, a0, a1, a2, a3);
    process_fb<3>(b0, b1, b2, b3, gg, li, lg, t0, cnt, c2s, cb, XbfT, Abf, msr);

    asm volatile("s_waitcnt lgkmcnt(0)" ::: "memory");
    FB af0, af1;
    const int abase = li * 64;
    const int asw   = (li & 7) + (li >> 3);
    af0.v = *(bf16x8*)&Abf[abase + (((lg + asw) & 7) << 3)];
    af1.v = *(bf16x8*)&Abf[abase + (((4 + lg + asw) & 7) << 3)];
    #pragma unroll
    for (int n = 0; n < 4; n++) {
      const int d  = n * 16 + li;
      const int dl = (li & 7) + 2 * n + (li >> 3);
      bf16x8 xb0 = *(bf16x8*)&XbfT[d * 64 + (((lg + dl) & 7) << 3)];
      acc[n] = __builtin_amdgcn_mfma_f32_16x16x32_bf16(af0.v, xb0, acc[n], 0, 0, 0);
      bf16x8 xb1 = *(bf16x8*)&XbfT[d * 64 + (((4 + lg + dl) & 7) << 3)];
      acc[n] = __builtin_amdgcn_mfma_f32_16x16x32_bf16(af1.v, xb1, acc[n], 0, 0, 0);
    }
    asm volatile("s_waitcnt lgkmcnt(0)" ::: "memory");
  }

  #pragma unroll
  for (int n = 0; n < 4; n++) {
    #pragma unroll
    for (int r = 0; r < 4; r++) {
      int cl = lg * 4 + r;
      if (cl < 8) Pf[(size_t)blockIdx.x * PROW + cl * 64 + n * 16 + li] = acc[n][r];
    }
  }
  msr += __shfl_xor(msr, 16);
  msr += __shfl_xor(msr, 32);
  if (lane < 8) Pf[(size_t)blockIdx.x * PROW + 512 + lane] = msr;
}

// ---------------- select source + coalesced reduce -> 256 rows ----------------
__global__ __launch_bounds__(64) void k_redsel1(const float* __restrict__ P4,
                                                const float* __restrict__ Pf,
                                                const int* __restrict__ cntp,
                                                float* __restrict__ P2) {
  const int cnt = *cntp;
  const float* S;
  int nrows;
  if (cnt >= 5) { S = P4 + (size_t)(cnt - 5) * GRID_F * PROW; nrows = GRID_F; }
  else          { S = Pf; nrows = GRID_FB; }
  const int b = blockIdx.x;  // 0..255
  for (int c = threadIdx.x; c < PROW; c += 64) {
    float s = 0.f;
    #pragma unroll
    for (int i = 0; i < 8; i++) {
      int row = b * 8 + i;
      if (row < nrows) s += S[(size_t)row * PROW + c];
    }
    P2[(size_t)b * PROW + c] = s;
  }
}

// ---------------- final reduce + normalize ----------------
__global__ __launch_bounds__(64) void k_red2(const float* __restrict__ P2,
                                             const int* __restrict__ cntp,
                                             float* __restrict__ out) {
  const int kd = blockIdx.x;  // 0..511
  const int k = kd >> 6;
  const int t = threadIdx.x;
  float s = 0.f, m = 0.f;
  #pragma unroll
  for (int i = 0; i < 4; i++) {
    int r = t + i * 64;
    s += P2[(size_t)r * PROW + kd];
    m += P2[(size_t)r * PROW + 512 + k];
  }
  for (int off = 1; off <= 32; off <<= 1) {
    s += __shfl_xor(s, off);
    m += __shfl_xor(m, off);
  }
  if (t == 0) {
    int cnt = *cntp;
    out[kd] = (k < cnt) ? s / (m + 1e-8f) : 0.f;
  }
}

extern "C" void kernel_launch(void* const* d_in, const int* in_sizes, int n_in,
                              void* d_out, int out_size, void* d_ws, size_t ws_size,
                              hipStream_t stream) {
  const float* embs = (const float*)d_in[0];
  const float* gum  = (const float*)d_in[1];
  const float* cent = (const float*)d_in[2];
  char* ws = (char*)d_ws;
  double* parta = (double*)(ws + OFF_PARTA);
  double* colf  = (double*)(ws + OFF_COLF);
  int*    cnt   = (int*)   (ws + OFF_CNT);
  float*  P4    = (float*) (ws + OFF_P4);
  float*  Pf    = (float*) (ws + OFF_PF);
  float*  P2    = (float*) (ws + OFF_P2);

  k_fused<<<GRID_F, 64, 0, stream>>>((const float4*)embs, gum, cent, parta, P4);
  k_colreduce<<<128, 256, 0, stream>>>(parta, colf);
  k_cnt<<<1, 64, 0, stream>>>(colf, cnt);
  k_fallback<<<GRID_FB, 64, 0, stream>>>((const float4*)embs, gum, cent, cnt, Pf);
  k_redsel1<<<256, 64, 0, stream>>>(P4, Pf, cnt, P2);
  k_red2<<<512, 64, 0, stream>>>(P2, cnt, (float*)d_out);
}